// Round 3
// baseline (56.267 us; speedup 1.0000x reference)
//
#include <hip/hip_runtime.h>

typedef __bf16 bf16x8 __attribute__((ext_vector_type(8)));
typedef float  f32x4  __attribute__((ext_vector_type(4)));

#define NB 1024
#define NN 128
#define NH 64
#define NOUT 128

__device__ __forceinline__ unsigned short f2b(float f) {
    return __builtin_bit_cast(unsigned short, (__bf16)f);
}

// One block per batch. 512 threads = 8 waves. 64 KB LDS -> 2 blocks/CU (16 waves/CU).
// LDS: adj[128][128] bf16 (256B rows) | hT[64][128] bf16 d-major (256B rows) |
//      S[128][64] bf16 (128B rows). All rows XOR-swizzled: byte ^= (row&7)<<4.
// All MFMA epilogues write packed ds_write_b64 (4 consecutive elements per lane).
__global__ __launch_bounds__(512, 4)
void rsgcn_fused(const int* __restrict__ graph, const float* __restrict__ adj,
                 const float* __restrict__ embed, const float* __restrict__ W1,
                 const float* __restrict__ W2, const float* __restrict__ W3,
                 float* __restrict__ out)
{
    __shared__ __align__(16) char smem[65536];
    char* const adj_s = smem;           // 32768 B
    char* const hT_s  = smem + 32768;   // 16384 B
    char* const S_s   = smem + 49152;   // 16384 B
    float* const part   = (float*)S_s;          // [512][4] staging column partials
    float* const colsum = (float*)S_s;          // [128] (S dead in epilogue)
    float* const svec   = (float*)(S_s + 512);  // [64]  (disjoint from colsum)

    const int b    = blockIdx.x;
    const int t    = threadIdx.x;
    const int lane = t & 63;
    const int wv   = t >> 6;

    // ---------------- issue all global loads first (hide HBM latency) --------
    const int jq = t & 31;                       // node quad: nodes 4*jq..+3
    const int dq = t >> 5;                       // d quad (0..15): d0 = 4*dq
    const int d0 = dq * 4;
    const int4 g4 = *(const int4*)(graph + b * NN + jq * 4);

    const float4* adj4 = (const float4*)(adj + (size_t)b * (NN * NN));
    float4 av[8];
    #pragma unroll
    for (int i = 0; i < 8; ++i) av[i] = adj4[i * 512 + t];

    float4 e0 = *(const float4*)(embed + g4.x * NH + d0);
    float4 e1 = *(const float4*)(embed + g4.y * NH + d0);
    float4 e2 = *(const float4*)(embed + g4.z * NH + d0);
    float4 e3 = *(const float4*)(embed + g4.w * NH + d0);

    // ---------------- stage adj: fp32 -> bf16 LDS + fp32 column partials ------
    {
        float p0 = 0.f, p1 = 0.f, p2 = 0.f, p3 = 0.f;
        #pragma unroll
        for (int i = 0; i < 8; ++i) {
            float4 v = av[i];
            p0 += v.x; p1 += v.y; p2 += v.z; p3 += v.w;
            int row  = i * 16 + dq;
            int colb = jq * 8;
            ushort4 u;
            u.x = f2b(v.x); u.y = f2b(v.y); u.z = f2b(v.z); u.w = f2b(v.w);
            *(ushort4*)(adj_s + row * 256 + (colb ^ ((row & 7) << 4))) = u;
        }
        *(float4*)(part + t * 4) = make_float4(p0, p1, p2, p3);
    }

    // ---------------- embed gather -> hT (packed b64 writes) ------------------
    {
        float ea[4][4];
        *(float4*)ea[0] = e0; *(float4*)ea[1] = e1;
        *(float4*)ea[2] = e2; *(float4*)ea[3] = e3;
        #pragma unroll
        for (int k = 0; k < 4; ++k) {
            int d = d0 + k;
            ushort4 u;
            u.x = f2b(ea[0][k]); u.y = f2b(ea[1][k]);
            u.z = f2b(ea[2][k]); u.w = f2b(ea[3][k]);
            *(ushort4*)(hT_s + d * 256 + ((jq * 8) ^ ((d & 7) << 4))) = u;
        }
    }

    // ---------------- preload W1,W2 MFMA B-fragments into registers -----------
    // B[k=d_in][n=d_out] = W[d_out][d_in]: lane: n = nt*16+(lane&15), k-octet (lane>>4)*8
    bf16x8 wf[2][8];   // [layer][nt*2+kk]
    #pragma unroll
    for (int L = 0; L < 2; ++L) {
        const float* W = L ? W2 : W1;
        #pragma unroll
        for (int nt = 0; nt < 4; ++nt) {
            #pragma unroll
            for (int kk = 0; kk < 2; ++kk) {
                const float4* p = (const float4*)(W + (nt * 16 + (lane & 15)) * NH
                                                  + kk * 32 + (lane >> 4) * 8);
                float4 v0 = p[0], v1 = p[1];
                bf16x8 a;
                a[0] = (__bf16)v0.x; a[1] = (__bf16)v0.y; a[2] = (__bf16)v0.z; a[3] = (__bf16)v0.w;
                a[4] = (__bf16)v1.x; a[5] = (__bf16)v1.y; a[6] = (__bf16)v1.z; a[7] = (__bf16)v1.w;
                wf[L][nt * 2 + kk] = a;
            }
        }
    }
    __syncthreads();

    // ---------------- reduce column partials -> per-thread colsum register ----
    float cs = 0.f;
    if (t < 128) {
        #pragma unroll
        for (int k = 0; k < 16; ++k)
            cs += part[(k * 32 + (t >> 2)) * 4 + (t & 3)];
    }
    __syncthreads();   // part (S region) dead; layers may overwrite S

    // ---------------- layers 1,2 ----------------------------------------------
    const int mtA  = wv & 3;              // matA: d-tile
    const int ntA0 = (wv >> 2) * 4;       // matA: node-tile base
    #pragma unroll
    for (int layer = 0; layer < 2; ++layer) {
        // ---- matA: S^T[d][node] = sum_j hT[d][j] * adj[node][j] --------------
        {
            f32x4 acc[4] = {};
            const int arow = mtA * 16 + (lane & 15);     // hT row (d)
            const int koff = (lane >> 4) * 16;           // byte offset of k-octet
            #pragma unroll
            for (int kk = 0; kk < 4; ++kk) {
                int kb = kk * 64 + koff;
                bf16x8 af = *(const bf16x8*)(hT_s + arow * 256 + (kb ^ ((arow & 7) << 4)));
                #pragma unroll
                for (int nt = 0; nt < 4; ++nt) {
                    int brow = (ntA0 + nt) * 16 + (lane & 15);   // adj row (node_out)
                    bf16x8 bf = *(const bf16x8*)(adj_s + brow * 256 + (kb ^ ((brow & 7) << 4)));
                    acc[nt] = __builtin_amdgcn_mfma_f32_16x16x32_bf16(af, bf, acc[nt], 0, 0, 0);
                }
            }
            // C: lane holds 4 consecutive d at node=(ntA0+nt)*16+(lane&15) -> b64
            const int dd0 = mtA * 16 + (lane >> 4) * 4;
            #pragma unroll
            for (int nt = 0; nt < 4; ++nt) {
                int node = (ntA0 + nt) * 16 + (lane & 15);
                ushort4 u;
                u.x = f2b(acc[nt][0]); u.y = f2b(acc[nt][1]);
                u.z = f2b(acc[nt][2]); u.w = f2b(acc[nt][3]);
                *(ushort4*)(S_s + node * 128 + ((dd0 * 2) ^ ((node & 7) << 4))) = u;
            }
        }
        __syncthreads();

        // ---- matB: h'[node][d_out] = sum_d S[node][d] * W[d_out][d] + relu ---
        {
            f32x4 acc[4] = {};
            const int arow = wv * 16 + (lane & 15);      // S row (node)
            const int koff = (lane >> 4) * 16;
            #pragma unroll
            for (int kk = 0; kk < 2; ++kk) {
                int kb = kk * 64 + koff;
                bf16x8 af = *(const bf16x8*)(S_s + arow * 128 + (kb ^ ((arow & 7) << 4)));
                #pragma unroll
                for (int nt = 0; nt < 4; ++nt)
                    acc[nt] = __builtin_amdgcn_mfma_f32_16x16x32_bf16(af, wf[layer][nt * 2 + kk],
                                                                      acc[nt], 0, 0, 0);
            }
            // C: lane holds 4 consecutive nodes at d_out=nt*16+(lane&15) -> b64 into hT
            const int node0 = wv * 16 + (lane >> 4) * 4;
            #pragma unroll
            for (int nt = 0; nt < 4; ++nt) {
                int dout = nt * 16 + (lane & 15);
                ushort4 u;
                u.x = f2b(fmaxf(acc[nt][0], 0.f)); u.y = f2b(fmaxf(acc[nt][1], 0.f));
                u.z = f2b(fmaxf(acc[nt][2], 0.f)); u.w = f2b(fmaxf(acc[nt][3], 0.f));
                *(ushort4*)(hT_s + dout * 256 + ((node0 * 2) ^ ((dout & 7) << 4))) = u;
            }
        }
        __syncthreads();
    }

    // ---------------- layer 3 collapsed: out = ((1^T adj) h2) W3^T ------------
    if (t < 128) colsum[t] = cs;
    __syncthreads();

    // svec[d] = sum_j colsum[j] * h2T[d][j]; 8 threads per d, shfl-reduce
    {
        const int d  = t >> 3;
        const int jj = t & 7;
        const int sw = (d & 7) << 4;
        bf16x8 h0 = *(const bf16x8*)(hT_s + d * 256 + ((jj * 32)      ^ sw));
        bf16x8 h1 = *(const bf16x8*)(hT_s + d * 256 + ((jj * 32 + 16) ^ sw));
        float p = 0.f;
        #pragma unroll
        for (int q = 0; q < 8; ++q) p += colsum[jj * 16 + q]     * (float)h0[q];
        #pragma unroll
        for (int q = 0; q < 8; ++q) p += colsum[jj * 16 + 8 + q] * (float)h1[q];
        p += __shfl_xor(p, 1);
        p += __shfl_xor(p, 2);
        p += __shfl_xor(p, 4);
        if (jj == 0) svec[d] = p;
    }
    __syncthreads();

    // out[b][o] = sum_d W3[o][d] * svec[d]   (fp32)
    if (t < 128) {
        const float4* wrow = (const float4*)(W3 + t * NH);
        float a0 = 0.f, a1 = 0.f;
        #pragma unroll
        for (int q = 0; q < 16; q += 2) {
            float4 w0 = wrow[q], w1 = wrow[q + 1];
            a0 += w0.x*svec[q*4+0] + w0.y*svec[q*4+1] + w0.z*svec[q*4+2] + w0.w*svec[q*4+3];
            a1 += w1.x*svec[q*4+4] + w1.y*svec[q*4+5] + w1.z*svec[q*4+6] + w1.w*svec[q*4+7];
        }
        out[b * NOUT + t] = a0 + a1;
    }
}

extern "C" void kernel_launch(void* const* d_in, const int* in_sizes, int n_in,
                              void* d_out, int out_size, void* d_ws, size_t ws_size,
                              hipStream_t stream) {
    const int*   graph = (const int*)d_in[0];
    const float* adjp  = (const float*)d_in[1];
    const float* embed = (const float*)d_in[2];
    const float* W1    = (const float*)d_in[3];
    const float* W2    = (const float*)d_in[4];
    const float* W3    = (const float*)d_in[5];
    float* outp = (float*)d_out;

    rsgcn_fused<<<dim3(NB), dim3(512), 0, stream>>>(graph, adjp, embed, W1, W2, W3, outp);
}

// Round 4
// 47.651 us; speedup vs baseline: 1.1808x; 1.1808x over previous
//
#include <hip/hip_runtime.h>

typedef __bf16 bf16x8 __attribute__((ext_vector_type(8)));
typedef float  f32x4  __attribute__((ext_vector_type(4)));

#define NB 1024
#define NN 128
#define NH 64
#define NOUT 128

__device__ __forceinline__ unsigned short f2b(float f) {
    return __builtin_bit_cast(unsigned short, (__bf16)f);
}

// One block per batch. 512 threads = 8 waves. 64 KB LDS -> 2 blocks/CU (16 waves/CU).
// LDS: adj[128][128] bf16 (256B rows) | hT[64][128] bf16 d-major (256B rows) |
//      S[128][64] bf16 (128B rows). All rows XOR-swizzled: byte ^= (row&7)<<4.
// All MFMA epilogues write packed ds_write_b64. No bulk register preloads (r3 spilled).
__global__ __launch_bounds__(512, 4)
void rsgcn_fused(const int* __restrict__ graph, const float* __restrict__ adj,
                 const float* __restrict__ embed, const float* __restrict__ W1,
                 const float* __restrict__ W2, const float* __restrict__ W3,
                 float* __restrict__ out)
{
    __shared__ __align__(16) char smem[65536];
    char* const adj_s = smem;           // 32768 B
    char* const hT_s  = smem + 32768;   // 16384 B
    char* const S_s   = smem + 49152;   // 16384 B
    float* const part   = (float*)S_s;          // [512][4] staging column partials
    float* const colsum = (float*)S_s;          // [128] (S dead in epilogue)
    float* const svec   = (float*)(S_s + 512);  // [64]

    const int b    = blockIdx.x;
    const int t    = threadIdx.x;
    const int lane = t & 63;
    const int wv   = t >> 6;

    const int jq = t & 31;                       // node quad: nodes 4*jq..+3
    const int dq = t >> 5;                       // d quad (0..15)
    const int d0 = dq * 4;

    // issue the gather-index load early (2-level dependent chain)
    const int4 g4 = *(const int4*)(graph + b * NN + jq * 4);

    // ---------------- stage adj: fp32 -> bf16 LDS + fp32 column partials ------
    // thread: rows {i*16+dq}, columns 4*jq..+3. Short live ranges (no spill).
    const float4* adj4 = (const float4*)(adj + (size_t)b * (NN * NN));
    {
        float p0 = 0.f, p1 = 0.f, p2 = 0.f, p3 = 0.f;
        #pragma unroll
        for (int i = 0; i < 8; ++i) {
            float4 v = adj4[i * 512 + t];
            p0 += v.x; p1 += v.y; p2 += v.z; p3 += v.w;
            int row  = i * 16 + dq;
            ushort4 u;
            u.x = f2b(v.x); u.y = f2b(v.y); u.z = f2b(v.z); u.w = f2b(v.w);
            *(ushort4*)(adj_s + row * 256 + ((jq * 8) ^ ((row & 7) << 4))) = u;
        }
        *(float4*)(part + t * 4) = make_float4(p0, p1, p2, p3);
    }

    // ---------------- embed gather -> hT (packed b64 writes) ------------------
    {
        float ea[4][4];
        *(float4*)ea[0] = *(const float4*)(embed + g4.x * NH + d0);
        *(float4*)ea[1] = *(const float4*)(embed + g4.y * NH + d0);
        *(float4*)ea[2] = *(const float4*)(embed + g4.z * NH + d0);
        *(float4*)ea[3] = *(const float4*)(embed + g4.w * NH + d0);
        #pragma unroll
        for (int k = 0; k < 4; ++k) {
            int d = d0 + k;
            ushort4 u;
            u.x = f2b(ea[0][k]); u.y = f2b(ea[1][k]);
            u.z = f2b(ea[2][k]); u.w = f2b(ea[3][k]);
            *(ushort4*)(hT_s + d * 256 + ((jq * 8) ^ ((d & 7) << 4))) = u;
        }
    }
    __syncthreads();

    // ---------------- reduce column partials -> per-thread colsum register ----
    float cs = 0.f;
    if (t < 128) {
        #pragma unroll
        for (int k = 0; k < 16; ++k)
            cs += part[(k * 32 + (t >> 2)) * 4 + (t & 3)];
    }
    __syncthreads();   // part (S region) dead; layers may overwrite S

    // ---------------- layers 1,2 ----------------------------------------------
    const int mtA  = wv & 3;              // matA: d-tile
    const int ntA0 = (wv >> 2) * 4;       // matA: node-tile base
    #pragma unroll
    for (int layer = 0; layer < 2; ++layer) {
        const float* W = layer ? W2 : W1;

        // W B-fragments for THIS layer only (32 VGPRs, L2-resident loads;
        // issued before matA so latency hides under the MFMAs)
        bf16x8 wf[8];   // [nt*2+kk]
        #pragma unroll
        for (int nt = 0; nt < 4; ++nt) {
            #pragma unroll
            for (int kk = 0; kk < 2; ++kk) {
                const float4* p = (const float4*)(W + (nt * 16 + (lane & 15)) * NH
                                                  + kk * 32 + (lane >> 4) * 8);
                float4 v0 = p[0], v1 = p[1];
                bf16x8 a;
                a[0] = (__bf16)v0.x; a[1] = (__bf16)v0.y; a[2] = (__bf16)v0.z; a[3] = (__bf16)v0.w;
                a[4] = (__bf16)v1.x; a[5] = (__bf16)v1.y; a[6] = (__bf16)v1.z; a[7] = (__bf16)v1.w;
                wf[nt * 2 + kk] = a;
            }
        }

        // ---- matA: S^T[d][node] = sum_j hT[d][j] * adj[node][j] --------------
        {
            f32x4 acc[4] = {};
            const int arow = mtA * 16 + (lane & 15);     // hT row (d)
            const int koff = (lane >> 4) * 16;           // byte offset of k-octet
            #pragma unroll
            for (int kk = 0; kk < 4; ++kk) {
                int kb = kk * 64 + koff;
                bf16x8 af = *(const bf16x8*)(hT_s + arow * 256 + (kb ^ ((arow & 7) << 4)));
                #pragma unroll
                for (int nt = 0; nt < 4; ++nt) {
                    int brow = (ntA0 + nt) * 16 + (lane & 15);   // adj row (node_out)
                    bf16x8 bf = *(const bf16x8*)(adj_s + brow * 256 + (kb ^ ((brow & 7) << 4)));
                    acc[nt] = __builtin_amdgcn_mfma_f32_16x16x32_bf16(af, bf, acc[nt], 0, 0, 0);
                }
            }
            // C: lane holds 4 consecutive d at node=(ntA0+nt)*16+(lane&15) -> b64
            const int dd0 = mtA * 16 + (lane >> 4) * 4;
            #pragma unroll
            for (int nt = 0; nt < 4; ++nt) {
                int node = (ntA0 + nt) * 16 + (lane & 15);
                ushort4 u;
                u.x = f2b(acc[nt][0]); u.y = f2b(acc[nt][1]);
                u.z = f2b(acc[nt][2]); u.w = f2b(acc[nt][3]);
                *(ushort4*)(S_s + node * 128 + ((dd0 * 2) ^ ((node & 7) << 4))) = u;
            }
        }
        __syncthreads();

        // ---- matB: h'[node][d_out] = sum_d S[node][d] * W[d_out][d] + relu ---
        {
            f32x4 acc[4] = {};
            const int arow = wv * 16 + (lane & 15);      // S row (node)
            const int koff = (lane >> 4) * 16;
            #pragma unroll
            for (int kk = 0; kk < 2; ++kk) {
                int kb = kk * 64 + koff;
                bf16x8 af = *(const bf16x8*)(S_s + arow * 128 + (kb ^ ((arow & 7) << 4)));
                #pragma unroll
                for (int nt = 0; nt < 4; ++nt)
                    acc[nt] = __builtin_amdgcn_mfma_f32_16x16x32_bf16(af, wf[nt * 2 + kk],
                                                                      acc[nt], 0, 0, 0);
            }
            // C: lane holds 4 consecutive nodes at d_out=nt*16+(lane&15) -> b64
            const int node0 = wv * 16 + (lane >> 4) * 4;
            #pragma unroll
            for (int nt = 0; nt < 4; ++nt) {
                int dout = nt * 16 + (lane & 15);
                ushort4 u;
                u.x = f2b(fmaxf(acc[nt][0], 0.f)); u.y = f2b(fmaxf(acc[nt][1], 0.f));
                u.z = f2b(fmaxf(acc[nt][2], 0.f)); u.w = f2b(fmaxf(acc[nt][3], 0.f));
                *(ushort4*)(hT_s + dout * 256 + ((node0 * 2) ^ ((dout & 7) << 4))) = u;
            }
        }
        __syncthreads();
    }

    // ---------------- layer 3 collapsed: out = ((1^T adj) h2) W3^T ------------
    if (t < 128) colsum[t] = cs;
    __syncthreads();

    // svec[d] = sum_j colsum[j] * h2T[d][j]; 8 threads per d, shfl-reduce
    {
        const int d  = t >> 3;
        const int jj = t & 7;
        const int sw = (d & 7) << 4;
        bf16x8 h0 = *(const bf16x8*)(hT_s + d * 256 + ((jj * 32)      ^ sw));
        bf16x8 h1 = *(const bf16x8*)(hT_s + d * 256 + ((jj * 32 + 16) ^ sw));
        float p = 0.f;
        #pragma unroll
        for (int q = 0; q < 8; ++q) p += colsum[jj * 16 + q]     * (float)h0[q];
        #pragma unroll
        for (int q = 0; q < 8; ++q) p += colsum[jj * 16 + 8 + q] * (float)h1[q];
        p += __shfl_xor(p, 1);
        p += __shfl_xor(p, 2);
        p += __shfl_xor(p, 4);
        if (jj == 0) svec[d] = p;
    }
    __syncthreads();

    // out[b][o] = sum_d W3[o][d] * svec[d]   (fp32)
    if (t < 128) {
        const float4* wrow = (const float4*)(W3 + t * NH);
        float a0 = 0.f, a1 = 0.f;
        #pragma unroll
        for (int q = 0; q < 16; q += 2) {
            float4 w0 = wrow[q], w1 = wrow[q + 1];
            a0 += w0.x*svec[q*4+0] + w0.y*svec[q*4+1] + w0.z*svec[q*4+2] + w0.w*svec[q*4+3];
            a1 += w1.x*svec[q*4+4] + w1.y*svec[q*4+5] + w1.z*svec[q*4+6] + w1.w*svec[q*4+7];
        }
        out[b * NOUT + t] = a0 + a1;
    }
}

extern "C" void kernel_launch(void* const* d_in, const int* in_sizes, int n_in,
                              void* d_out, int out_size, void* d_ws, size_t ws_size,
                              hipStream_t stream) {
    const int*   graph = (const int*)d_in[0];
    const float* adjp  = (const float*)d_in[1];
    const float* embed = (const float*)d_in[2];
    const float* W1    = (const float*)d_in[3];
    const float* W2    = (const float*)d_in[4];
    const float* W3    = (const float*)d_in[5];
    float* outp = (float*)d_out;

    rsgcn_fused<<<dim3(NB), dim3(512), 0, stream>>>(graph, adjp, embed, W1, W2, W3, outp);
}

// Round 5
// 38.931 us; speedup vs baseline: 1.4453x; 1.2240x over previous
//
#include <hip/hip_runtime.h>

typedef __bf16 bf16x8 __attribute__((ext_vector_type(8)));
typedef float  f32x4  __attribute__((ext_vector_type(4)));

#define NB 1024
#define NN 128
#define NH 64
#define NOUT 128

__device__ __forceinline__ unsigned short f2b(float f) {
    return __builtin_bit_cast(unsigned short, (__bf16)f);
}

// One block per batch, 256 threads = 4 waves, 4 blocks/CU.
// adj is NEVER staged in LDS: each wave reads its 32-node slab directly from
// global in MFMA B-fragment layout (dense 64B sectors), converts once, and
// holds it in 32 VGPRs of bf16 fragments reused by all 3 matA passes.
// LDS: hT[64][128] bf16 (256B rows) | S[128][64] bf16 (128B rows), XOR-swizzled.
// Layer 3 collapsed: svec[d] = sum_n (adj @ h2)[n][d] via cross-lane reduce of
// matA accumulators; out = svec @ W3^T.
__global__ __launch_bounds__(256, 4)
void rsgcn_fused(const int* __restrict__ graph, const float* __restrict__ adj,
                 const float* __restrict__ embed, const float* __restrict__ W1,
                 const float* __restrict__ W2, const float* __restrict__ W3,
                 float* __restrict__ out)
{
    __shared__ __align__(16) char smem[32768];
    char* const hT_s = smem;            // 16384 B
    char* const S_s  = smem + 16384;    // 16384 B
    float* const svecp = (float*)S_s;          // [4][64] per-wave partials (S dead)
    float* const svec  = (float*)(S_s + 1024); // [64]

    const int b    = blockIdx.x;
    const int t    = threadIdx.x;
    const int lane = t & 63;
    const int wv   = t >> 6;
    const int l15  = lane & 15;
    const int lg   = lane >> 4;

    // ---- issue the wave's adj slab: 32 nodes x 128 j, fp32, fragment layout --
    // per (kk,nt,h): lane reads 16B at row (wv*32+nt*16+l15), col (kk*32+lg*8+h*4)
    // -> each instruction covers 16 rows x 64B contiguous (dense sectors).
    const float* adjb = adj + (size_t)b * (NN * NN);
    float4 av[16];
    #pragma unroll
    for (int kk = 0; kk < 4; ++kk)
        #pragma unroll
        for (int nt = 0; nt < 2; ++nt)
            #pragma unroll
            for (int h = 0; h < 2; ++h) {
                int row = wv * 32 + nt * 16 + l15;
                int col = kk * 32 + lg * 8 + h * 4;
                av[(kk * 2 + nt) * 2 + h] = *(const float4*)(adjb + row * NN + col);
            }

    // ---- embed gather -> hT (packed b64 writes) ------------------------------
    {
        const int jq = t & 31;            // nodes 4*jq..+3
        const int d0 = (t >> 5) * 8;      // 8 features per thread
        const int4 g4 = *(const int4*)(graph + b * NN + jq * 4);
        float ea[4][8];
        *(float4*)&ea[0][0] = *(const float4*)(embed + g4.x * NH + d0);
        *(float4*)&ea[0][4] = *(const float4*)(embed + g4.x * NH + d0 + 4);
        *(float4*)&ea[1][0] = *(const float4*)(embed + g4.y * NH + d0);
        *(float4*)&ea[1][4] = *(const float4*)(embed + g4.y * NH + d0 + 4);
        *(float4*)&ea[2][0] = *(const float4*)(embed + g4.z * NH + d0);
        *(float4*)&ea[2][4] = *(const float4*)(embed + g4.z * NH + d0 + 4);
        *(float4*)&ea[3][0] = *(const float4*)(embed + g4.w * NH + d0);
        *(float4*)&ea[3][4] = *(const float4*)(embed + g4.w * NH + d0 + 4);
        #pragma unroll
        for (int k = 0; k < 8; ++k) {
            int d = d0 + k;
            ushort4 u;
            u.x = f2b(ea[0][k]); u.y = f2b(ea[1][k]);
            u.z = f2b(ea[2][k]); u.w = f2b(ea[3][k]);
            *(ushort4*)(hT_s + d * 256 + ((jq * 8) ^ ((d & 7) << 4))) = u;
        }
    }

    // ---- convert adj slab to bf16 fragments (lives across all 3 layers) -----
    bf16x8 af[4][2];
    #pragma unroll
    for (int kk = 0; kk < 4; ++kk)
        #pragma unroll
        for (int nt = 0; nt < 2; ++nt) {
            float4 v0 = av[(kk * 2 + nt) * 2 + 0];
            float4 v1 = av[(kk * 2 + nt) * 2 + 1];
            bf16x8 a;
            a[0] = (__bf16)v0.x; a[1] = (__bf16)v0.y; a[2] = (__bf16)v0.z; a[3] = (__bf16)v0.w;
            a[4] = (__bf16)v1.x; a[5] = (__bf16)v1.y; a[6] = (__bf16)v1.z; a[7] = (__bf16)v1.w;
            af[kk][nt] = a;
        }
    __syncthreads();

    // ---- layers 1,2: h' = relu((adj @ h) @ W^T) ------------------------------
    #pragma unroll
    for (int layer = 0; layer < 2; ++layer) {
        const float* W = layer ? W2 : W1;

        // matA: S^T[d][node] = sum_j hT[d][j] * adj[node][j]
        {
            f32x4 acc[4][2] = {};
            #pragma unroll
            for (int kk = 0; kk < 4; ++kk) {
                bf16x8 ha[4];
                #pragma unroll
                for (int dt = 0; dt < 4; ++dt) {
                    int r = dt * 16 + l15;
                    ha[dt] = *(const bf16x8*)(hT_s + r * 256 + ((kk * 64 + lg * 16) ^ ((r & 7) << 4)));
                }
                #pragma unroll
                for (int nt = 0; nt < 2; ++nt)
                    #pragma unroll
                    for (int dt = 0; dt < 4; ++dt)
                        acc[dt][nt] = __builtin_amdgcn_mfma_f32_16x16x32_bf16(
                            ha[dt], af[kk][nt], acc[dt][nt], 0, 0, 0);
            }
            // write S[node][d]: lane holds 4 consecutive d at node = base+l15
            #pragma unroll
            for (int dt = 0; dt < 4; ++dt)
                #pragma unroll
                for (int nt = 0; nt < 2; ++nt) {
                    int node = wv * 32 + nt * 16 + l15;
                    int dd0  = dt * 16 + lg * 4;
                    ushort4 u;
                    u.x = f2b(acc[dt][nt][0]); u.y = f2b(acc[dt][nt][1]);
                    u.z = f2b(acc[dt][nt][2]); u.w = f2b(acc[dt][nt][3]);
                    *(ushort4*)(S_s + node * 128 + ((dd0 * 2) ^ ((node & 7) << 4))) = u;
                }
        }
        __syncthreads();

        // matB: h'[node][dout] = relu( sum_d S[node][d] * W[dout][d] )
        {
            f32x4 acc2[2][4] = {};
            #pragma unroll
            for (int k2 = 0; k2 < 2; ++k2) {
                bf16x8 wf[4];
                #pragma unroll
                for (int dt = 0; dt < 4; ++dt) {
                    const float4* p = (const float4*)(W + (dt * 16 + l15) * NH + k2 * 32 + lg * 8);
                    float4 v0 = p[0], v1 = p[1];
                    bf16x8 a;
                    a[0] = (__bf16)v0.x; a[1] = (__bf16)v0.y; a[2] = (__bf16)v0.z; a[3] = (__bf16)v0.w;
                    a[4] = (__bf16)v1.x; a[5] = (__bf16)v1.y; a[6] = (__bf16)v1.z; a[7] = (__bf16)v1.w;
                    wf[dt] = a;
                }
                #pragma unroll
                for (int nt = 0; nt < 2; ++nt) {
                    int row = wv * 32 + nt * 16 + l15;
                    bf16x8 sa = *(const bf16x8*)(S_s + row * 128 + ((k2 * 64 + lg * 16) ^ ((row & 7) << 4)));
                    #pragma unroll
                    for (int dt = 0; dt < 4; ++dt)
                        acc2[nt][dt] = __builtin_amdgcn_mfma_f32_16x16x32_bf16(
                            sa, wf[dt], acc2[nt][dt], 0, 0, 0);
                }
            }
            // write hT[dout][node]: lane holds 4 consecutive nodes at dout
            #pragma unroll
            for (int nt = 0; nt < 2; ++nt)
                #pragma unroll
                for (int dt = 0; dt < 4; ++dt) {
                    int dout  = dt * 16 + l15;
                    int node0 = wv * 32 + nt * 16 + lg * 4;
                    ushort4 u;
                    u.x = f2b(fmaxf(acc2[nt][dt][0], 0.f));
                    u.y = f2b(fmaxf(acc2[nt][dt][1], 0.f));
                    u.z = f2b(fmaxf(acc2[nt][dt][2], 0.f));
                    u.w = f2b(fmaxf(acc2[nt][dt][3], 0.f));
                    *(ushort4*)(hT_s + dout * 256 + ((node0 * 2) ^ ((dout & 7) << 4))) = u;
                }
        }
        __syncthreads();
    }

    // ---- layer 3: svec[d] = sum_node (adj @ h2)^T[d][node] -------------------
    {
        f32x4 acc3[4][2] = {};
        #pragma unroll
        for (int kk = 0; kk < 4; ++kk) {
            bf16x8 ha[4];
            #pragma unroll
            for (int dt = 0; dt < 4; ++dt) {
                int r = dt * 16 + l15;
                ha[dt] = *(const bf16x8*)(hT_s + r * 256 + ((kk * 64 + lg * 16) ^ ((r & 7) << 4)));
            }
            #pragma unroll
            for (int nt = 0; nt < 2; ++nt)
                #pragma unroll
                for (int dt = 0; dt < 4; ++dt)
                    acc3[dt][nt] = __builtin_amdgcn_mfma_f32_16x16x32_bf16(
                        ha[dt], af[kk][nt], acc3[dt][nt], 0, 0, 0);
        }
        // reduce over this wave's 32 nodes: nt pair (VALU) + 16-lane shuffle tree
        float s[4][4];
        #pragma unroll
        for (int dt = 0; dt < 4; ++dt)
            #pragma unroll
            for (int i = 0; i < 4; ++i)
                s[dt][i] = acc3[dt][0][i] + acc3[dt][1][i];
        #pragma unroll
        for (int m = 1; m <= 8; m <<= 1)
            #pragma unroll
            for (int dt = 0; dt < 4; ++dt)
                #pragma unroll
                for (int i = 0; i < 4; ++i)
                    s[dt][i] += __shfl_xor(s[dt][i], m);
        if (l15 == 0) {
            #pragma unroll
            for (int dt = 0; dt < 4; ++dt) {
                f32x4 sv = {s[dt][0], s[dt][1], s[dt][2], s[dt][3]};
                *(f32x4*)(svecp + wv * 64 + dt * 16 + lg * 4) = sv;
            }
        }
    }
    __syncthreads();

    if (t < 64) svec[t] = (svecp[t] + svecp[64 + t]) + (svecp[128 + t] + svecp[192 + t]);
    __syncthreads();

    // ---- out[b][o] = sum_d W3[o][d] * svec[d] (fp32) -------------------------
    if (t < 128) {
        const float4* wrow = (const float4*)(W3 + t * NH);
        float a0 = 0.f, a1 = 0.f;
        #pragma unroll
        for (int q = 0; q < 16; q += 2) {
            float4 w0 = wrow[q], w1 = wrow[q + 1];
            a0 += w0.x*svec[q*4+0] + w0.y*svec[q*4+1] + w0.z*svec[q*4+2] + w0.w*svec[q*4+3];
            a1 += w1.x*svec[q*4+4] + w1.y*svec[q*4+5] + w1.z*svec[q*4+6] + w1.w*svec[q*4+7];
        }
        out[b * NOUT + t] = a0 + a1;
    }
}

extern "C" void kernel_launch(void* const* d_in, const int* in_sizes, int n_in,
                              void* d_out, int out_size, void* d_ws, size_t ws_size,
                              hipStream_t stream) {
    const int*   graph = (const int*)d_in[0];
    const float* adjp  = (const float*)d_in[1];
    const float* embed = (const float*)d_in[2];
    const float* W1    = (const float*)d_in[3];
    const float* W2    = (const float*)d_in[4];
    const float* W3    = (const float*)d_in[5];
    float* outp = (float*)d_out;

    rsgcn_fused<<<dim3(NB), dim3(256), 0, stream>>>(graph, adjp, embed, W1, W2, W3, outp);
}